// Round 1
// baseline (646.152 us; speedup 1.0000x reference)
//
#include <hip/hip_runtime.h>
#include <math.h>

#define BB 32
#define NN 8400
#define MM 32
#define NC 80
#define PD 85
#define TOPK 10

__device__ __forceinline__ float sigmoidf_(float x) { return 1.0f / (1.0f + expf(-x)); }
__device__ __forceinline__ float bcef_(float x, float t) {
    return fmaxf(x, 0.0f) - x * t + log1pf(expf(-fabsf(x)));
}

// ---- Kernel A: per-prediction precompute -------------------------------
__global__ void kA(const float* __restrict__ pred,
                   float4* __restrict__ pxyxy, float2* __restrict__ cxy,
                   float* __restrict__ objsig, float* __restrict__ base) {
    int i = blockIdx.x * 256 + threadIdx.x;
    if (i >= BB * NN) return;
    const float* p = pred + (size_t)i * PD;
    float cx = p[0], cy = p[1], w = p[2], h = p[3];
    pxyxy[i] = make_float4(cx - w * 0.5f, cy - h * 0.5f, cx + w * 0.5f, cy + h * 0.5f);
    cxy[i] = make_float2(cx, cy);
    float so = sigmoidf_(p[4]);
    objsig[i] = so;
    float b_ = 0.0f;
    for (int c = 0; c < NC; ++c) {
        float s = sqrtf(sigmoidf_(p[5 + c]) * so);
        b_ -= logf(1.0f - s + 1e-7f);
    }
    base[i] = b_;
}

// ---- Kernel B: pairwise cost matrix ------------------------------------
__global__ void kB(const float* __restrict__ pred, const float* __restrict__ tgt,
                   const float4* __restrict__ pxyxy, const float2* __restrict__ cxy,
                   const float* __restrict__ objsig, const float* __restrict__ base,
                   float* __restrict__ cost) {
    int n = blockIdx.x * 256 + threadIdx.x;
    int g = blockIdx.y, b = blockIdx.z;
    if (n >= NN) return;
    const float* t = tgt + ((size_t)b * MM + g) * 5;
    int gcls = (int)t[0];
    float gx1 = t[1] - t[3] * 0.5f, gy1 = t[2] - t[4] * 0.5f;
    float gx2 = t[1] + t[3] * 0.5f, gy2 = t[2] + t[4] * 0.5f;
    float ga = fmaxf(gx2 - gx1, 0.0f) * fmaxf(gy2 - gy1, 0.0f);

    size_t pi = (size_t)b * NN + n;
    float4 pb = pxyxy[pi];
    float2 c = cxy[pi];

    float ix1 = fmaxf(gx1, pb.x), iy1 = fmaxf(gy1, pb.y);
    float ix2 = fminf(gx2, pb.z), iy2 = fminf(gy2, pb.w);
    float inter = fmaxf(ix2 - ix1, 0.0f) * fmaxf(iy2 - iy1, 0.0f);
    float pa = fmaxf(pb.z - pb.x, 0.0f) * fmaxf(pb.w - pb.y, 0.0f);
    float uni = ga + pa - inter + 1e-7f;
    float iou = inter / uni;
    bool inb = (c.x > gx1) && (c.x < gx2) && (c.y > gy1) && (c.y < gy2);

    float cl = pred[pi * PD + 5 + gcls];
    float s = sqrtf(sigmoidf_(cl) * objsig[pi]);
    float lp = logf(s + 1e-7f);
    float lq = logf(1.0f - s + 1e-7f);
    float cc = base[pi] - lp + lq;
    float co = cc + 3.0f * (-logf(iou + 1e-8f)) + (inb ? 0.0f : 100000.0f);
    cost[((size_t)b * MM + g) * NN + n] = co;
}

// ---- Kernel C: per-GT dyn_k + assignment --------------------------------
__global__ void kC(const float* __restrict__ cost, const float* __restrict__ tgt,
                   const float4* __restrict__ pxyxy, unsigned int* __restrict__ mask) {
    const int g = blockIdx.x, b = blockIdx.y, tid = threadIdx.x;
    const float* crow = cost + ((size_t)b * MM + g) * NN;
    const float* t = tgt + ((size_t)b * MM + g) * 5;
    float gx1 = t[1] - t[3] * 0.5f, gy1 = t[2] - t[4] * 0.5f;
    float gx2 = t[1] + t[3] * 0.5f, gy2 = t[2] + t[4] * 0.5f;
    float ga = fmaxf(gx2 - gx1, 0.0f) * fmaxf(gy2 - gy1, 0.0f);

    __shared__ float sval[256];
    __shared__ int sidx[256];
    __shared__ int sel[TOPK];
    __shared__ float ssum_sh;
    __shared__ int dynk_sh;
    if (tid == 0) ssum_sh = 0.0f;
    __syncthreads();

    // Phase 1: sum of top-10 (iou * in_box)  -> dyn_k
    for (int p = 0; p < TOPK; ++p) {
        float bv = -1.0f;
        int bi = 0x7fffffff;
        for (int n = tid; n < NN; n += 256) {
            bool skip = false;
            for (int q = 0; q < p; ++q) skip |= (sel[q] == n);
            if (skip) continue;
            float4 pb = pxyxy[(size_t)b * NN + n];
            float ix1 = fmaxf(gx1, pb.x), iy1 = fmaxf(gy1, pb.y);
            float ix2 = fminf(gx2, pb.z), iy2 = fminf(gy2, pb.w);
            float inter = fmaxf(ix2 - ix1, 0.0f) * fmaxf(iy2 - iy1, 0.0f);
            float pa = fmaxf(pb.z - pb.x, 0.0f) * fmaxf(pb.w - pb.y, 0.0f);
            float iou = inter / (ga + pa - inter + 1e-7f);
            bool inb = crow[n] < 5.0e4f;  // in-box cost << 5e4, out-box >= ~1e5
            float v = inb ? iou : 0.0f;
            if (v > bv || (v == bv && n < bi)) { bv = v; bi = n; }
        }
        sval[tid] = bv; sidx[tid] = bi;
        __syncthreads();
        for (int off = 128; off > 0; off >>= 1) {
            if (tid < off) {
                float v2 = sval[tid + off]; int i2 = sidx[tid + off];
                if (v2 > sval[tid] || (v2 == sval[tid] && i2 < sidx[tid])) {
                    sval[tid] = v2; sidx[tid] = i2;
                }
            }
            __syncthreads();
        }
        if (tid == 0) { sel[p] = sidx[0]; ssum_sh += sval[0]; }
        __syncthreads();
    }
    if (tid == 0) {
        int k = (int)ssum_sh;          // trunc toward zero (sum >= 0)
        if (k < 1) k = 1;
        if (k > TOPK) k = TOPK;        // sum of top-10 ious < 10 strictly
        dynk_sh = k;
    }
    __syncthreads();
    const int dynk = dynk_sh;

    // Phase 2: dyn_k smallest costs (stable tie-break by index == JAX double-argsort)
    for (int p = 0; p < dynk; ++p) {
        float bv = 3.4e38f;
        int bi = 0x7fffffff;
        for (int n = tid; n < NN; n += 256) {
            bool skip = false;
            for (int q = 0; q < p; ++q) skip |= (sel[q] == n);
            if (skip) continue;
            float v = crow[n];
            if (v < bv || (v == bv && n < bi)) { bv = v; bi = n; }
        }
        sval[tid] = bv; sidx[tid] = bi;
        __syncthreads();
        for (int off = 128; off > 0; off >>= 1) {
            if (tid < off) {
                float v2 = sval[tid + off]; int i2 = sidx[tid + off];
                if (v2 < sval[tid] || (v2 == sval[tid] && i2 < sidx[tid])) {
                    sval[tid] = v2; sidx[tid] = i2;
                }
            }
            __syncthreads();
        }
        if (tid == 0) {
            int idx = sidx[0];
            sel[p] = idx;
            if (sval[0] < 5.0e4f)  // assigned requires in_box
                atomicOr(&mask[(size_t)b * NN + idx], 1u << g);
        }
        __syncthreads();
    }
}

// ---- Kernel D: per-prediction losses -> per-block partials ---------------
__global__ void kD(const float* __restrict__ pred, const float* __restrict__ tgt,
                   const float4* __restrict__ pxyxy, const unsigned int* __restrict__ mask,
                   const float* __restrict__ cost, float* __restrict__ partials) {
    int i = blockIdx.x * 256 + threadIdx.x;
    float obj_l = 0.0f, cls_l = 0.0f, reg_l = 0.0f, nfg = 0.0f;
    if (i < BB * NN) {
        int b = i / NN;
        int n = i - b * NN;
        unsigned int mk = mask[i];
        float fg = mk ? 1.0f : 0.0f;
        const float* p = pred + (size_t)i * PD;
        obj_l = bcef_(p[4], fg);
        if (mk) {
            nfg = 1.0f;
            float best = 3.0e30f;
            int bg = 0;
            for (int g = 0; g < MM; ++g) {
                if ((mk >> g) & 1u) {
                    float cv = cost[((size_t)b * MM + g) * NN + n];
                    if (cv < best) { best = cv; bg = g; }  // strict: first-min tie rule
                }
            }
            const float* t = tgt + ((size_t)b * MM + bg) * 5;
            int gcls = (int)t[0];
            for (int c = 0; c < NC; ++c)
                cls_l += bcef_(p[5 + c], (c == gcls) ? 1.0f : 0.0f);
            // giou(pxyxy[n], gxyxy[bg])
            float tx1 = t[1] - t[3] * 0.5f, ty1 = t[2] - t[4] * 0.5f;
            float tx2 = t[1] + t[3] * 0.5f, ty2 = t[2] + t[4] * 0.5f;
            float4 pb = pxyxy[i];
            float ix1 = fmaxf(pb.x, tx1), iy1 = fmaxf(pb.y, ty1);
            float ix2 = fminf(pb.z, tx2), iy2 = fminf(pb.w, ty2);
            float inter = fmaxf(ix2 - ix1, 0.0f) * fmaxf(iy2 - iy1, 0.0f);
            float pa = fmaxf(pb.z - pb.x, 0.0f) * fmaxf(pb.w - pb.y, 0.0f);
            float ta = fmaxf(tx2 - tx1, 0.0f) * fmaxf(ty2 - ty1, 0.0f);
            float uni = pa + ta - inter + 1e-7f;
            float iou = inter / uni;
            float ex1 = fminf(pb.x, tx1), ey1 = fminf(pb.y, ty1);
            float ex2 = fmaxf(pb.z, tx2), ey2 = fmaxf(pb.w, ty2);
            float enclose = (ex2 - ex1) * (ey2 - ey1) + 1e-7f;
            float giou = iou - (enclose - uni) / enclose;
            reg_l = 1.0f - giou;
        }
    }
    __shared__ float red[256];
    float sums[4] = {cls_l, obj_l, reg_l, nfg};
    float out4[4];
    for (int j = 0; j < 4; ++j) {
        red[threadIdx.x] = sums[j];
        __syncthreads();
        for (int off = 128; off > 0; off >>= 1) {
            if (threadIdx.x < off) red[threadIdx.x] += red[threadIdx.x + off];
            __syncthreads();
        }
        out4[j] = red[0];
        __syncthreads();
    }
    if (threadIdx.x == 0) {
        float* pr = partials + (size_t)blockIdx.x * 4;
        pr[0] = out4[0]; pr[1] = out4[1]; pr[2] = out4[2]; pr[3] = out4[3];
    }
}

// ---- Kernel E: final deterministic reduction -----------------------------
__global__ void kE(const float* __restrict__ partials, int nblk, float* __restrict__ out) {
    __shared__ float red[256];
    float s[4] = {0, 0, 0, 0};
    for (int i = threadIdx.x; i < nblk; i += 256) {
        s[0] += partials[(size_t)i * 4 + 0];
        s[1] += partials[(size_t)i * 4 + 1];
        s[2] += partials[(size_t)i * 4 + 2];
        s[3] += partials[(size_t)i * 4 + 3];
    }
    float tot[4];
    for (int j = 0; j < 4; ++j) {
        red[threadIdx.x] = s[j];
        __syncthreads();
        for (int off = 128; off > 0; off >>= 1) {
            if (threadIdx.x < off) red[threadIdx.x] += red[threadIdx.x + off];
            __syncthreads();
        }
        tot[j] = red[0];
        __syncthreads();
    }
    if (threadIdx.x == 0) {
        float nfg = fmaxf(tot[3], 1.0f);
        out[0] = (tot[0] + tot[1] + 5.0f * tot[2]) / nfg;
    }
}

extern "C" void kernel_launch(void* const* d_in, const int* in_sizes, int n_in,
                              void* d_out, int out_size, void* d_ws, size_t ws_size,
                              hipStream_t stream) {
    const float* pred = (const float*)d_in[0];   // (B, N, 85) f32
    const float* tgt  = (const float*)d_in[1];   // (B, M, 5)  f32
    float* out = (float*)d_out;

    // Workspace layout (all 16B-aligned; total ~45 MB)
    char* ws = (char*)d_ws;
    size_t off = 0;
    float* cost = (float*)(ws + off);            off += (size_t)BB * MM * NN * sizeof(float);
    float4* pxyxy = (float4*)(ws + off);         off += (size_t)BB * NN * sizeof(float4);
    float2* cxy = (float2*)(ws + off);           off += (size_t)BB * NN * sizeof(float2);
    float* objsig = (float*)(ws + off);          off += (size_t)BB * NN * sizeof(float);
    float* base = (float*)(ws + off);            off += (size_t)BB * NN * sizeof(float);
    unsigned int* mask = (unsigned int*)(ws + off); off += (size_t)BB * NN * sizeof(unsigned int);
    float* partials = (float*)(ws + off);

    const int nblk = (BB * NN + 255) / 256;  // 1050

    // mask accumulates via atomicOr -> must be zeroed every call
    hipMemsetAsync(mask, 0, (size_t)BB * NN * sizeof(unsigned int), stream);

    kA<<<nblk, 256, 0, stream>>>(pred, pxyxy, cxy, objsig, base);

    dim3 gB((NN + 255) / 256, MM, BB);
    kB<<<gB, 256, 0, stream>>>(pred, tgt, pxyxy, cxy, objsig, base, cost);

    dim3 gC(MM, BB);
    kC<<<gC, 256, 0, stream>>>(cost, tgt, pxyxy, mask);

    kD<<<nblk, 256, 0, stream>>>(pred, tgt, pxyxy, mask, cost, partials);

    kE<<<1, 256, 0, stream>>>(partials, nblk, out);
}

// Round 2
// 346.894 us; speedup vs baseline: 1.8627x; 1.8627x over previous
//
#include <hip/hip_runtime.h>
#include <math.h>

#define BB 32
#define NN 8400
#define MM 32
#define NC 80
#define PD 85
#define TOPK 10
#define FLT_BIG 3.4e38f

__device__ __forceinline__ float sigmoidf_(float x) { return 1.0f / (1.0f + expf(-x)); }
__device__ __forceinline__ float bcef_(float x, float t) {
    return fmaxf(x, 0.0f) - x * t + log1pf(expf(-fabsf(x)));
}

// ---- Kernel AB: fused per-prediction precompute + full cost matrix -------
// One thread = one prediction row; loops all 32 GTs with GT constants in LDS.
__global__ void kAB(const float* __restrict__ pred, const float* __restrict__ tgt,
                    float4* __restrict__ pxyxy, float* __restrict__ objlogit,
                    float* __restrict__ cost) {
    const int n = blockIdx.x * 256 + threadIdx.x;
    const int b = blockIdx.y;
    __shared__ float sgx1[MM], sgy1[MM], sgx2[MM], sgy2[MM], sga[MM];
    __shared__ int sgc[MM];
    if (threadIdx.x < MM) {
        const float* t = tgt + ((size_t)b * MM + threadIdx.x) * 5;
        float x1 = t[1] - t[3] * 0.5f, y1 = t[2] - t[4] * 0.5f;
        float x2 = t[1] + t[3] * 0.5f, y2 = t[2] + t[4] * 0.5f;
        sgx1[threadIdx.x] = x1; sgy1[threadIdx.x] = y1;
        sgx2[threadIdx.x] = x2; sgy2[threadIdx.x] = y2;
        sga[threadIdx.x] = fmaxf(x2 - x1, 0.0f) * fmaxf(y2 - y1, 0.0f);
        sgc[threadIdx.x] = (int)t[0];
    }
    __syncthreads();
    if (n >= NN) return;

    const size_t pi = (size_t)b * NN + n;
    const float* p = pred + pi * PD;
    float cx = p[0], cy = p[1], w = p[2], h = p[3], ol = p[4];
    float px1 = cx - w * 0.5f, py1 = cy - h * 0.5f;
    float px2 = cx + w * 0.5f, py2 = cy + h * 0.5f;
    pxyxy[pi] = make_float4(px1, py1, px2, py2);
    objlogit[pi] = ol;
    float so = sigmoidf_(ol);
    float base = 0.0f;
    for (int c = 0; c < NC; ++c) {
        float s = sqrtf(sigmoidf_(p[5 + c]) * so);
        base -= logf(1.0f - s + 1e-7f);
    }
    float pa = fmaxf(px2 - px1, 0.0f) * fmaxf(py2 - py1, 0.0f);

    for (int g = 0; g < MM; ++g) {
        float gx1 = sgx1[g], gy1 = sgy1[g], gx2 = sgx2[g], gy2 = sgy2[g];
        float ix1 = fmaxf(gx1, px1), iy1 = fmaxf(gy1, py1);
        float ix2 = fminf(gx2, px2), iy2 = fminf(gy2, py2);
        float inter = fmaxf(ix2 - ix1, 0.0f) * fmaxf(iy2 - iy1, 0.0f);
        float uni = sga[g] + pa - inter + 1e-7f;
        float iou = inter / uni;
        bool inb = (cx > gx1) && (cx < gx2) && (cy > gy1) && (cy < gy2);
        float cl = p[5 + sgc[g]];
        float s = sqrtf(sigmoidf_(cl) * so);
        float lp = logf(s + 1e-7f);
        float lq = logf(1.0f - s + 1e-7f);
        float cc = base - lp + lq;
        float co = cc + 3.0f * (-logf(iou + 1e-8f)) + (inb ? 0.0f : 100000.0f);
        cost[((size_t)b * MM + g) * NN + n] = co;
    }
}

// ---- Kernel C: per-GT dyn_k + assignment, single-pass selection ----------
__global__ void __launch_bounds__(256) kC(const float* __restrict__ cost,
                                          const float* __restrict__ tgt,
                                          const float4* __restrict__ pxyxy,
                                          unsigned int* __restrict__ mask) {
    const int g = blockIdx.x, b = blockIdx.y, tid = threadIdx.x;
    const int wid = tid >> 6, lane = tid & 63;
    const float* crow = cost + ((size_t)b * MM + g) * NN;
    const float* t = tgt + ((size_t)b * MM + g) * 5;
    float gx1 = t[1] - t[3] * 0.5f, gy1 = t[2] - t[4] * 0.5f;
    float gx2 = t[1] + t[3] * 0.5f, gy2 = t[2] + t[4] * 0.5f;
    float ga = fmaxf(gx2 - gx1, 0.0f) * fmaxf(gy2 - gy1, 0.0f);

    // per-thread candidate lists (registers, static indexing only)
    float ti[TOPK];                 // top ious, descending
    float cv[TOPK]; int ci[TOPK];   // bottom costs ascending, lex (v, idx)
    #pragma unroll
    for (int j = 0; j < TOPK; ++j) { ti[j] = -1.0f; cv[j] = FLT_BIG; ci[j] = 0x7fffffff; }

    // single pass over the row
    for (int n = tid; n < NN; n += 256) {
        float4 pb = pxyxy[(size_t)b * NN + n];
        float ix1 = fmaxf(gx1, pb.x), iy1 = fmaxf(gy1, pb.y);
        float ix2 = fminf(gx2, pb.z), iy2 = fminf(gy2, pb.w);
        float inter = fmaxf(ix2 - ix1, 0.0f) * fmaxf(iy2 - iy1, 0.0f);
        float pa = fmaxf(pb.z - pb.x, 0.0f) * fmaxf(pb.w - pb.y, 0.0f);
        float iou = inter / (ga + pa - inter + 1e-7f);
        float c = crow[n];
        float v = (c < 5.0e4f) ? iou : 0.0f;   // in-box <=> cost << 5e4
        if (v > ti[TOPK - 1]) {
            ti[TOPK - 1] = v;
            #pragma unroll
            for (int j = TOPK - 1; j > 0; --j)
                if (ti[j] > ti[j - 1]) { float tmp = ti[j - 1]; ti[j - 1] = ti[j]; ti[j] = tmp; }
        }
        // scan order is increasing n per thread -> strict < keeps stable (v, idx) order
        if (c < cv[TOPK - 1]) {
            cv[TOPK - 1] = c; ci[TOPK - 1] = n;
            #pragma unroll
            for (int j = TOPK - 1; j > 0; --j)
                if (cv[j] < cv[j - 1]) {
                    float tv = cv[j - 1]; cv[j - 1] = cv[j]; cv[j] = tv;
                    int tn = ci[j - 1]; ci[j - 1] = ci[j]; ci[j] = tn;
                }
        }
    }

    __shared__ float lv[256 * TOPK];
    __shared__ int   li[256 * TOPK];
    __shared__ float wv[4]; __shared__ int wn[4], wp[4];
    __shared__ float s_sum; __shared__ int s_dynk;

    // ---- Phase 1 merge: sum of global top-10 ious (descending add order) --
    #pragma unroll
    for (int j = 0; j < TOPK; ++j) lv[tid + 256 * j] = ti[j];
    __syncthreads();
    for (int p = 0; p < TOPK; ++p) {
        float bv = -2.0f; int bp = -1;
        #pragma unroll
        for (int j = 0; j < TOPK; ++j) {
            int idx = tid + 256 * j; float v = lv[idx];
            if (v > bv) { bv = v; bp = idx; }
        }
        for (int off = 32; off; off >>= 1) {
            float ov = __shfl_xor(bv, off); int op = __shfl_xor(bp, off);
            if (ov > bv || (ov == bv && op < bp)) { bv = ov; bp = op; }
        }
        if (lane == 0) { wv[wid] = bv; wp[wid] = bp; }
        __syncthreads();
        if (tid == 0) {
            float mb = wv[0]; int mp = wp[0];
            for (int w2 = 1; w2 < 4; ++w2)
                if (wv[w2] > mb || (wv[w2] == mb && wp[w2] < mp)) { mb = wv[w2]; mp = wp[w2]; }
            s_sum = (p == 0) ? mb : (s_sum + mb);
            lv[mp] = -2.0f;
        }
        __syncthreads();
    }
    if (tid == 0) {
        int k = (int)s_sum;          // trunc toward zero, sum >= 0
        if (k < 1) k = 1;
        if (k > TOPK) k = TOPK;
        s_dynk = k;
    }

    // ---- Phase 2 merge: dyn_k lexicographically-smallest (cost, idx) ------
    #pragma unroll
    for (int j = 0; j < TOPK; ++j) { lv[tid + 256 * j] = cv[j]; li[tid + 256 * j] = ci[j]; }
    __syncthreads();
    const int dynk = s_dynk;
    for (int p = 0; p < dynk; ++p) {
        float bv = FLT_BIG; int bn = 0x7fffffff; int bp = -1;
        #pragma unroll
        for (int j = 0; j < TOPK; ++j) {
            int idx = tid + 256 * j; float v = lv[idx]; int nn2 = li[idx];
            if (v < bv || (v == bv && nn2 < bn)) { bv = v; bn = nn2; bp = idx; }
        }
        for (int off = 32; off; off >>= 1) {
            float ov = __shfl_xor(bv, off);
            int on = __shfl_xor(bn, off);
            int op = __shfl_xor(bp, off);
            if (ov < bv || (ov == bv && on < bn)) { bv = ov; bn = on; bp = op; }
        }
        if (lane == 0) { wv[wid] = bv; wn[wid] = bn; wp[wid] = bp; }
        __syncthreads();
        if (tid == 0) {
            float mb = wv[0]; int mn = wn[0], mp = wp[0];
            for (int w2 = 1; w2 < 4; ++w2)
                if (wv[w2] < mb || (wv[w2] == mb && wn[w2] < mn)) { mb = wv[w2]; mn = wn[w2]; mp = wp[w2]; }
            lv[mp] = FLT_BIG; li[mp] = 0x7fffffff;
            if (mb < 5.0e4f)  // assigned requires in_box
                atomicOr(&mask[(size_t)b * NN + mn], 1u << g);
        }
        __syncthreads();
    }
}

// ---- Kernel D: per-prediction losses -> per-block partials ---------------
__global__ void kD(const float* __restrict__ pred, const float* __restrict__ tgt,
                   const float4* __restrict__ pxyxy, const float* __restrict__ objlogit,
                   const unsigned int* __restrict__ mask,
                   const float* __restrict__ cost, float* __restrict__ partials) {
    int i = blockIdx.x * 256 + threadIdx.x;
    float obj_l = 0.0f, cls_l = 0.0f, reg_l = 0.0f, nfg = 0.0f;
    if (i < BB * NN) {
        int b = i / NN;
        int n = i - b * NN;
        unsigned int mk = mask[i];
        float fg = mk ? 1.0f : 0.0f;
        obj_l = bcef_(objlogit[i], fg);
        if (mk) {
            nfg = 1.0f;
            float best = 3.0e30f;
            int bg = 0;
            for (int g = 0; g < MM; ++g) {
                if ((mk >> g) & 1u) {
                    float cv = cost[((size_t)b * MM + g) * NN + n];
                    if (cv < best) { best = cv; bg = g; }  // strict: first-min tie rule
                }
            }
            const float* p = pred + (size_t)i * PD;
            const float* t = tgt + ((size_t)b * MM + bg) * 5;
            int gcls = (int)t[0];
            for (int c = 0; c < NC; ++c)
                cls_l += bcef_(p[5 + c], (c == gcls) ? 1.0f : 0.0f);
            float tx1 = t[1] - t[3] * 0.5f, ty1 = t[2] - t[4] * 0.5f;
            float tx2 = t[1] + t[3] * 0.5f, ty2 = t[2] + t[4] * 0.5f;
            float4 pb = pxyxy[i];
            float ix1 = fmaxf(pb.x, tx1), iy1 = fmaxf(pb.y, ty1);
            float ix2 = fminf(pb.z, tx2), iy2 = fminf(pb.w, ty2);
            float inter = fmaxf(ix2 - ix1, 0.0f) * fmaxf(iy2 - iy1, 0.0f);
            float pa = fmaxf(pb.z - pb.x, 0.0f) * fmaxf(pb.w - pb.y, 0.0f);
            float ta = fmaxf(tx2 - tx1, 0.0f) * fmaxf(ty2 - ty1, 0.0f);
            float uni = pa + ta - inter + 1e-7f;
            float iou = inter / uni;
            float ex1 = fminf(pb.x, tx1), ey1 = fminf(pb.y, ty1);
            float ex2 = fmaxf(pb.z, tx2), ey2 = fmaxf(pb.w, ty2);
            float enclose = (ex2 - ex1) * (ey2 - ey1) + 1e-7f;
            float giou = iou - (enclose - uni) / enclose;
            reg_l = 1.0f - giou;
        }
    }
    __shared__ float red[256];
    float sums[4] = {cls_l, obj_l, reg_l, nfg};
    float out4[4];
    for (int j = 0; j < 4; ++j) {
        red[threadIdx.x] = sums[j];
        __syncthreads();
        for (int off = 128; off > 0; off >>= 1) {
            if (threadIdx.x < off) red[threadIdx.x] += red[threadIdx.x + off];
            __syncthreads();
        }
        out4[j] = red[0];
        __syncthreads();
    }
    if (threadIdx.x == 0) {
        float* pr = partials + (size_t)blockIdx.x * 4;
        pr[0] = out4[0]; pr[1] = out4[1]; pr[2] = out4[2]; pr[3] = out4[3];
    }
}

// ---- Kernel E: final deterministic reduction -----------------------------
__global__ void kE(const float* __restrict__ partials, int nblk, float* __restrict__ out) {
    __shared__ float red[256];
    float s[4] = {0, 0, 0, 0};
    for (int i = threadIdx.x; i < nblk; i += 256) {
        s[0] += partials[(size_t)i * 4 + 0];
        s[1] += partials[(size_t)i * 4 + 1];
        s[2] += partials[(size_t)i * 4 + 2];
        s[3] += partials[(size_t)i * 4 + 3];
    }
    float tot[4];
    for (int j = 0; j < 4; ++j) {
        red[threadIdx.x] = s[j];
        __syncthreads();
        for (int off = 128; off > 0; off >>= 1) {
            if (threadIdx.x < off) red[threadIdx.x] += red[threadIdx.x + off];
            __syncthreads();
        }
        tot[j] = red[0];
        __syncthreads();
    }
    if (threadIdx.x == 0) {
        float nfg = fmaxf(tot[3], 1.0f);
        out[0] = (tot[0] + tot[1] + 5.0f * tot[2]) / nfg;
    }
}

extern "C" void kernel_launch(void* const* d_in, const int* in_sizes, int n_in,
                              void* d_out, int out_size, void* d_ws, size_t ws_size,
                              hipStream_t stream) {
    const float* pred = (const float*)d_in[0];   // (B, N, 85) f32
    const float* tgt  = (const float*)d_in[1];   // (B, M, 5)  f32
    float* out = (float*)d_out;

    // Workspace layout (~40 MB)
    char* ws = (char*)d_ws;
    size_t off = 0;
    float* cost = (float*)(ws + off);               off += (size_t)BB * MM * NN * sizeof(float);
    float4* pxyxy = (float4*)(ws + off);            off += (size_t)BB * NN * sizeof(float4);
    float* objlogit = (float*)(ws + off);           off += (size_t)BB * NN * sizeof(float);
    unsigned int* mask = (unsigned int*)(ws + off); off += (size_t)BB * NN * sizeof(unsigned int);
    float* partials = (float*)(ws + off);

    const int nblk = (BB * NN + 255) / 256;  // 1050

    // mask accumulates via atomicOr -> must be zeroed every call
    hipMemsetAsync(mask, 0, (size_t)BB * NN * sizeof(unsigned int), stream);

    dim3 gAB((NN + 255) / 256, BB);
    kAB<<<gAB, 256, 0, stream>>>(pred, tgt, pxyxy, objlogit, cost);

    dim3 gC(MM, BB);
    kC<<<gC, 256, 0, stream>>>(cost, tgt, pxyxy, mask);

    kD<<<nblk, 256, 0, stream>>>(pred, tgt, pxyxy, objlogit, mask, cost, partials);

    kE<<<1, 256, 0, stream>>>(partials, nblk, out);
}

// Round 3
// 275.515 us; speedup vs baseline: 2.3452x; 1.2591x over previous
//
#include <hip/hip_runtime.h>
#include <math.h>

#define BB 32
#define NN 8400
#define MM 32
#define NC 80
#define PD 85
#define TOPK 10
#define RPB 128               // pred rows per kAB block
#define FLT_BIG 3.4e38f

__device__ __forceinline__ float sigmoidf_(float x) { return 1.0f / (1.0f + expf(-x)); }
__device__ __forceinline__ float bcef_(float x, float t) {
    return fmaxf(x, 0.0f) - x * t + log1pf(expf(-fabsf(x)));
}

// ---- Kernel AB: LDS-staged per-prediction precompute + cost/viou matrices ----
// Block = 128 threads = 128 pred rows. Stage 128*85 floats coalesced via float4
// (block region is contiguous & 16B-aligned), then thread-per-row compute from
// LDS (row stride 85 floats -> 2-way bank aliasing only, free).
__global__ void __launch_bounds__(RPB) kAB(const float* __restrict__ pred,
                                           const float* __restrict__ tgt,
                                           float* __restrict__ objlogit,
                                           float* __restrict__ cost,
                                           float* __restrict__ viou) {
    const int b = blockIdx.y;
    const int row0 = blockIdx.x * RPB;
    const int vr = min(RPB, NN - row0);          // 128 or 80, both %4 == 0
    const int tid = threadIdx.x;

    __shared__ float sm[RPB * PD];
    __shared__ float sgx1[MM], sgy1[MM], sgx2[MM], sgy2[MM], sga[MM];
    __shared__ int sgc[MM];

    if (tid < MM) {
        const float* t = tgt + ((size_t)b * MM + tid) * 5;
        float x1 = t[1] - t[3] * 0.5f, y1 = t[2] - t[4] * 0.5f;
        float x2 = t[1] + t[3] * 0.5f, y2 = t[2] + t[4] * 0.5f;
        sgx1[tid] = x1; sgy1[tid] = y1; sgx2[tid] = x2; sgy2[tid] = y2;
        sga[tid] = fmaxf(x2 - x1, 0.0f) * fmaxf(y2 - y1, 0.0f);
        sgc[tid] = (int)t[0];
    }

    // coalesced float4 stage of vr full rows
    {
        const float4* src4 = (const float4*)(pred + ((size_t)b * NN + row0) * PD);
        float4* dst4 = (float4*)sm;
        const int n4 = vr * PD / 4;              // 2720 or 1700
        for (int i = tid; i < n4; i += RPB) dst4[i] = src4[i];
    }
    __syncthreads();

    if (tid >= vr) return;
    const int n = row0 + tid;
    const size_t pi = (size_t)b * NN + n;
    const float* p = sm + tid * PD;

    float cx = p[0], cy = p[1], w = p[2], h = p[3], ol = p[4];
    float px1 = cx - w * 0.5f, py1 = cy - h * 0.5f;
    float px2 = cx + w * 0.5f, py2 = cy + h * 0.5f;
    objlogit[pi] = ol;
    float so = sigmoidf_(ol);
    float base = 0.0f;
    for (int c = 0; c < NC; ++c) {
        float s = sqrtf(sigmoidf_(p[5 + c]) * so);
        base -= logf(1.0f - s + 1e-7f);
    }
    float pa = fmaxf(px2 - px1, 0.0f) * fmaxf(py2 - py1, 0.0f);

    for (int g = 0; g < MM; ++g) {
        float gx1 = sgx1[g], gy1 = sgy1[g], gx2 = sgx2[g], gy2 = sgy2[g];
        float ix1 = fmaxf(gx1, px1), iy1 = fmaxf(gy1, py1);
        float ix2 = fminf(gx2, px2), iy2 = fminf(gy2, py2);
        float inter = fmaxf(ix2 - ix1, 0.0f) * fmaxf(iy2 - iy1, 0.0f);
        float uni = sga[g] + pa - inter + 1e-7f;
        float iou = inter / uni;
        bool inb = (cx > gx1) && (cx < gx2) && (cy > gy1) && (cy < gy2);
        float cl = p[5 + sgc[g]];
        float s = sqrtf(sigmoidf_(cl) * so);
        float lp = logf(s + 1e-7f);
        float lq = logf(1.0f - s + 1e-7f);
        float cc = base - lp + lq;
        float co = cc + 3.0f * (-logf(iou + 1e-8f)) + (inb ? 0.0f : 100000.0f);
        size_t o = ((size_t)b * MM + g) * NN + n;
        cost[o] = co;
        viou[o] = inb ? iou : 0.0f;   // == iou * in_box (reference multiplies by mask)
    }
}

// ---- Kernel C: per-GT dyn_k + assignment, single-pass 2-stream selection ----
__global__ void __launch_bounds__(256) kC(const float* __restrict__ cost,
                                          const float* __restrict__ viou,
                                          unsigned int* __restrict__ mask) {
    const int g = blockIdx.x, b = blockIdx.y, tid = threadIdx.x;
    const int wid = tid >> 6, lane = tid & 63;
    const size_t rowo = ((size_t)b * MM + g) * NN;
    const float* crow = cost + rowo;
    const float* vrow = viou + rowo;

    // per-thread candidate lists (registers, static indexing only)
    float ti[TOPK];                 // top ious, descending
    float cv[TOPK]; int ci[TOPK];   // smallest costs, lex (v, idx) ascending
    #pragma unroll
    for (int j = 0; j < TOPK; ++j) { ti[j] = -1.0f; cv[j] = FLT_BIG; ci[j] = 0x7fffffff; }

    for (int n = tid; n < NN; n += 256) {
        float v = vrow[n];
        float c = crow[n];
        if (v > ti[TOPK - 1]) {
            ti[TOPK - 1] = v;
            #pragma unroll
            for (int j = TOPK - 1; j > 0; --j)
                if (ti[j] > ti[j - 1]) { float tmp = ti[j - 1]; ti[j - 1] = ti[j]; ti[j] = tmp; }
        }
        // per-thread scan order is increasing n -> strict < keeps stable (v, idx)
        if (c < cv[TOPK - 1]) {
            cv[TOPK - 1] = c; ci[TOPK - 1] = n;
            #pragma unroll
            for (int j = TOPK - 1; j > 0; --j)
                if (cv[j] < cv[j - 1]) {
                    float tv = cv[j - 1]; cv[j - 1] = cv[j]; cv[j] = tv;
                    int tn = ci[j - 1]; ci[j - 1] = ci[j]; ci[j] = tn;
                }
        }
    }

    __shared__ float lv[256 * TOPK];
    __shared__ int   li[256 * TOPK];
    __shared__ float wv[4]; __shared__ int wn[4], wp[4];
    __shared__ float s_sum; __shared__ int s_dynk;

    // ---- Phase 1 merge: sum of global top-10 ious (descending add order) --
    #pragma unroll
    for (int j = 0; j < TOPK; ++j) lv[tid + 256 * j] = ti[j];
    __syncthreads();
    for (int p = 0; p < TOPK; ++p) {
        float bv = -2.0f; int bp = -1;
        #pragma unroll
        for (int j = 0; j < TOPK; ++j) {
            int idx = tid + 256 * j; float v = lv[idx];
            if (v > bv) { bv = v; bp = idx; }
        }
        for (int off = 32; off; off >>= 1) {
            float ov = __shfl_xor(bv, off); int op = __shfl_xor(bp, off);
            if (ov > bv || (ov == bv && op < bp)) { bv = ov; bp = op; }
        }
        if (lane == 0) { wv[wid] = bv; wp[wid] = bp; }
        __syncthreads();
        if (tid == 0) {
            float mb = wv[0]; int mp = wp[0];
            for (int w2 = 1; w2 < 4; ++w2)
                if (wv[w2] > mb || (wv[w2] == mb && wp[w2] < mp)) { mb = wv[w2]; mp = wp[w2]; }
            s_sum = (p == 0) ? mb : (s_sum + mb);
            lv[mp] = -2.0f;
        }
        __syncthreads();
    }
    if (tid == 0) {
        int k = (int)s_sum;          // trunc toward zero, sum >= 0
        if (k < 1) k = 1;
        if (k > TOPK) k = TOPK;
        s_dynk = k;
    }

    // ---- Phase 2 merge: dyn_k lexicographically-smallest (cost, idx) ------
    #pragma unroll
    for (int j = 0; j < TOPK; ++j) { lv[tid + 256 * j] = cv[j]; li[tid + 256 * j] = ci[j]; }
    __syncthreads();
    const int dynk = s_dynk;
    for (int p = 0; p < dynk; ++p) {
        float bv = FLT_BIG; int bn = 0x7fffffff; int bp = -1;
        #pragma unroll
        for (int j = 0; j < TOPK; ++j) {
            int idx = tid + 256 * j; float v = lv[idx]; int nn2 = li[idx];
            if (v < bv || (v == bv && nn2 < bn)) { bv = v; bn = nn2; bp = idx; }
        }
        for (int off = 32; off; off >>= 1) {
            float ov = __shfl_xor(bv, off);
            int on = __shfl_xor(bn, off);
            int op = __shfl_xor(bp, off);
            if (ov < bv || (ov == bv && on < bn)) { bv = ov; bn = on; bp = op; }
        }
        if (lane == 0) { wv[wid] = bv; wn[wid] = bn; wp[wid] = bp; }
        __syncthreads();
        if (tid == 0) {
            float mb = wv[0]; int mn = wn[0], mp = wp[0];
            for (int w2 = 1; w2 < 4; ++w2)
                if (wv[w2] < mb || (wv[w2] == mb && wn[w2] < mn)) { mb = wv[w2]; mn = wn[w2]; mp = wp[w2]; }
            lv[mp] = FLT_BIG; li[mp] = 0x7fffffff;
            if (mb < 5.0e4f)  // assigned requires in_box (in-box cost << 5e4)
                atomicOr(&mask[(size_t)b * NN + mn], 1u << g);
        }
        __syncthreads();
    }
}

// ---- Kernel D: per-prediction losses -> per-block partials ---------------
__global__ void kD(const float* __restrict__ pred, const float* __restrict__ tgt,
                   const float* __restrict__ objlogit,
                   const unsigned int* __restrict__ mask,
                   const float* __restrict__ cost, float* __restrict__ partials) {
    int i = blockIdx.x * 256 + threadIdx.x;
    float obj_l = 0.0f, cls_l = 0.0f, reg_l = 0.0f, nfg = 0.0f;
    if (i < BB * NN) {
        int b = i / NN;
        int n = i - b * NN;
        unsigned int mk = mask[i];
        float fg = mk ? 1.0f : 0.0f;
        obj_l = bcef_(objlogit[i], fg);
        if (mk) {
            nfg = 1.0f;
            float best = 3.0e30f;
            int bg = 0;
            for (int g = 0; g < MM; ++g) {
                if ((mk >> g) & 1u) {
                    float cv = cost[((size_t)b * MM + g) * NN + n];
                    if (cv < best) { best = cv; bg = g; }  // strict: first-min tie rule
                }
            }
            const float* p = pred + (size_t)i * PD;
            const float* t = tgt + ((size_t)b * MM + bg) * 5;
            int gcls = (int)t[0];
            for (int c = 0; c < NC; ++c)
                cls_l += bcef_(p[5 + c], (c == gcls) ? 1.0f : 0.0f);
            float cx = p[0], cy = p[1], w = p[2], h = p[3];
            float px1 = cx - w * 0.5f, py1 = cy - h * 0.5f;
            float px2 = cx + w * 0.5f, py2 = cy + h * 0.5f;
            float tx1 = t[1] - t[3] * 0.5f, ty1 = t[2] - t[4] * 0.5f;
            float tx2 = t[1] + t[3] * 0.5f, ty2 = t[2] + t[4] * 0.5f;
            float ix1 = fmaxf(px1, tx1), iy1 = fmaxf(py1, ty1);
            float ix2 = fminf(px2, tx2), iy2 = fminf(py2, ty2);
            float inter = fmaxf(ix2 - ix1, 0.0f) * fmaxf(iy2 - iy1, 0.0f);
            float pa = fmaxf(px2 - px1, 0.0f) * fmaxf(py2 - py1, 0.0f);
            float ta = fmaxf(tx2 - tx1, 0.0f) * fmaxf(ty2 - ty1, 0.0f);
            float uni = pa + ta - inter + 1e-7f;
            float iou = inter / uni;
            float ex1 = fminf(px1, tx1), ey1 = fminf(py1, ty1);
            float ex2 = fmaxf(px2, tx2), ey2 = fmaxf(py2, ty2);
            float enclose = (ex2 - ex1) * (ey2 - ey1) + 1e-7f;
            float giou = iou - (enclose - uni) / enclose;
            reg_l = 1.0f - giou;
        }
    }
    __shared__ float red[256];
    float sums[4] = {cls_l, obj_l, reg_l, nfg};
    float out4[4];
    for (int j = 0; j < 4; ++j) {
        red[threadIdx.x] = sums[j];
        __syncthreads();
        for (int off = 128; off > 0; off >>= 1) {
            if (threadIdx.x < off) red[threadIdx.x] += red[threadIdx.x + off];
            __syncthreads();
        }
        out4[j] = red[0];
        __syncthreads();
    }
    if (threadIdx.x == 0) {
        float* pr = partials + (size_t)blockIdx.x * 4;
        pr[0] = out4[0]; pr[1] = out4[1]; pr[2] = out4[2]; pr[3] = out4[3];
    }
}

// ---- Kernel E: final deterministic reduction -----------------------------
__global__ void kE(const float* __restrict__ partials, int nblk, float* __restrict__ out) {
    __shared__ float red[256];
    float s[4] = {0, 0, 0, 0};
    for (int i = threadIdx.x; i < nblk; i += 256) {
        s[0] += partials[(size_t)i * 4 + 0];
        s[1] += partials[(size_t)i * 4 + 1];
        s[2] += partials[(size_t)i * 4 + 2];
        s[3] += partials[(size_t)i * 4 + 3];
    }
    float tot[4];
    for (int j = 0; j < 4; ++j) {
        red[threadIdx.x] = s[j];
        __syncthreads();
        for (int off = 128; off > 0; off >>= 1) {
            if (threadIdx.x < off) red[threadIdx.x] += red[threadIdx.x + off];
            __syncthreads();
        }
        tot[j] = red[0];
        __syncthreads();
    }
    if (threadIdx.x == 0) {
        float nfg = fmaxf(tot[3], 1.0f);
        out[0] = (tot[0] + tot[1] + 5.0f * tot[2]) / nfg;
    }
}

extern "C" void kernel_launch(void* const* d_in, const int* in_sizes, int n_in,
                              void* d_out, int out_size, void* d_ws, size_t ws_size,
                              hipStream_t stream) {
    const float* pred = (const float*)d_in[0];   // (B, N, 85) f32
    const float* tgt  = (const float*)d_in[1];   // (B, M, 5)  f32
    float* out = (float*)d_out;

    // Workspace layout (~71 MB)
    char* ws = (char*)d_ws;
    size_t off = 0;
    float* cost = (float*)(ws + off);               off += (size_t)BB * MM * NN * sizeof(float);
    float* viou = (float*)(ws + off);               off += (size_t)BB * MM * NN * sizeof(float);
    float* objlogit = (float*)(ws + off);           off += (size_t)BB * NN * sizeof(float);
    unsigned int* mask = (unsigned int*)(ws + off); off += (size_t)BB * NN * sizeof(unsigned int);
    float* partials = (float*)(ws + off);

    const int nblk = (BB * NN + 255) / 256;  // 1050

    // mask accumulates via atomicOr -> must be zeroed every call
    hipMemsetAsync(mask, 0, (size_t)BB * NN * sizeof(unsigned int), stream);

    dim3 gAB((NN + RPB - 1) / RPB, BB);      // 66 x 32
    kAB<<<gAB, RPB, 0, stream>>>(pred, tgt, objlogit, cost, viou);

    dim3 gC(MM, BB);
    kC<<<gC, 256, 0, stream>>>(cost, viou, mask);

    kD<<<nblk, 256, 0, stream>>>(pred, tgt, objlogit, mask, cost, partials);

    kE<<<1, 256, 0, stream>>>(partials, nblk, out);
}